// Round 10
// baseline (116.179 us; speedup 1.0000x reference)
//
#include <hip/hip_runtime.h>

#define NN 512
#define DD 768
#define EPSF 1e-8f
#define TI 8
#define JCHUNK 16
#define JBLK (NN / JCHUNK)   // 32
#define IBLK (NN / TI)       // 64
#define NBLOCKS (IBLK * (JBLK + 1))  // 2112
#define THREADS 192
#define LN2 0.6931471805599453
#define LOG2E 1.4426950408889634f

#define RLOG2(x) __builtin_amdgcn_logf(x)
#define REXP2(x) __builtin_amdgcn_exp2f(x)

typedef float v2f __attribute__((ext_vector_type(2)));
union F4 { float4 f; v2f h[2]; };

// ws layout (bytes):
//   acc    @ 0   : acc[0] unused, acc[1] = Cd (diag, log2 units), acc[2] = Ct raw (sum s*log2 s)
//   ticket @ 64  : uint, k_cross completion counter
//   hrow   @ 128 : 1024 doubles (per-row H, log2 units; plain stores, no init needed)
//   p1     @ 32768 : 512*768 floats;  p2 after p1
// acc/ticket zero-initialized by k_softmax block 0 (kernel boundary orders it before k_cross).
//
// Cross identity:  sum_d s*log2(s/2+eps) = sum_d s*log2(s) - sum_d s + eps-term;
// summed over (i,j): sum s = 2*N^2 exactly, eps term -> 2*EPS*D*N^2/ln2 (analytic).

// One WAVE per row. 12 elements/lane, shuffle-only reductions.
__global__ __launch_bounds__(256) void k_softmax(
    const float* __restrict__ z1, const float* __restrict__ z2,
    float* __restrict__ p1, float* __restrict__ p2, double* __restrict__ hrow,
    double* __restrict__ acc, unsigned int* __restrict__ ticket) {
    int t = threadIdx.x;
    int lane = t & 63, w = t >> 6;
    int r = blockIdx.x * 4 + w;
    if (blockIdx.x == 0 && t == 0) {
        acc[0] = 0.0; acc[1] = 0.0; acc[2] = 0.0; *ticket = 0u;
    }
    const float* z = (r < NN) ? (z1 + (size_t)r * DD) : (z2 + (size_t)(r - NN) * DD);
    float*       p = (r < NN) ? (p1 + (size_t)r * DD) : (p2 + (size_t)(r - NN) * DD);

    float4 v0 = *(const float4*)(z + 4 * lane);
    float4 v1 = *(const float4*)(z + 256 + 4 * lane);
    float4 v2 = *(const float4*)(z + 512 + 4 * lane);

    float m = fmaxf(fmaxf(fmaxf(v0.x, v0.y), fmaxf(v0.z, v0.w)),
             fmaxf(fmaxf(fmaxf(v1.x, v1.y), fmaxf(v1.z, v1.w)),
                   fmaxf(fmaxf(v2.x, v2.y), fmaxf(v2.z, v2.w))));
    #pragma unroll
    for (int o = 32; o; o >>= 1) m = fmaxf(m, __shfl_xor(m, o, 64));

    float mb = -m * LOG2E;
    float4 e0, e1, e2;
    e0.x = REXP2(fmaf(v0.x, LOG2E, mb)); e0.y = REXP2(fmaf(v0.y, LOG2E, mb));
    e0.z = REXP2(fmaf(v0.z, LOG2E, mb)); e0.w = REXP2(fmaf(v0.w, LOG2E, mb));
    e1.x = REXP2(fmaf(v1.x, LOG2E, mb)); e1.y = REXP2(fmaf(v1.y, LOG2E, mb));
    e1.z = REXP2(fmaf(v1.z, LOG2E, mb)); e1.w = REXP2(fmaf(v1.w, LOG2E, mb));
    e2.x = REXP2(fmaf(v2.x, LOG2E, mb)); e2.y = REXP2(fmaf(v2.y, LOG2E, mb));
    e2.z = REXP2(fmaf(v2.z, LOG2E, mb)); e2.w = REXP2(fmaf(v2.w, LOG2E, mb));

    double s = ((double)e0.x + (double)e0.y) + ((double)e0.z + (double)e0.w)
             + ((double)e1.x + (double)e1.y) + ((double)e1.z + (double)e1.w)
             + ((double)e2.x + (double)e2.y) + ((double)e2.z + (double)e2.w);
    #pragma unroll
    for (int o = 32; o; o >>= 1) s += __shfl_xor(s, o, 64);
    float invS = 1.0f / (float)s;

    float4 q0, q1, q2;
    q0.x = e0.x * invS; q0.y = e0.y * invS; q0.z = e0.z * invS; q0.w = e0.w * invS;
    q1.x = e1.x * invS; q1.y = e1.y * invS; q1.z = e1.z * invS; q1.w = e1.w * invS;
    q2.x = e2.x * invS; q2.y = e2.y * invS; q2.z = e2.z * invS; q2.w = e2.w * invS;
    *(float4*)(p + 4 * lane) = q0;
    *(float4*)(p + 256 + 4 * lane) = q1;
    *(float4*)(p + 512 + 4 * lane) = q2;

    float hf = 0.0f;
    hf = fmaf(q0.x, RLOG2(q0.x + EPSF), hf); hf = fmaf(q0.y, RLOG2(q0.y + EPSF), hf);
    hf = fmaf(q0.z, RLOG2(q0.z + EPSF), hf); hf = fmaf(q0.w, RLOG2(q0.w + EPSF), hf);
    hf = fmaf(q1.x, RLOG2(q1.x + EPSF), hf); hf = fmaf(q1.y, RLOG2(q1.y + EPSF), hf);
    hf = fmaf(q1.z, RLOG2(q1.z + EPSF), hf); hf = fmaf(q1.w, RLOG2(q1.w + EPSF), hf);
    hf = fmaf(q2.x, RLOG2(q2.x + EPSF), hf); hf = fmaf(q2.y, RLOG2(q2.y + EPSF), hf);
    hf = fmaf(q2.z, RLOG2(q2.z + EPSF), hf); hf = fmaf(q2.w, RLOG2(q2.w + EPSF), hf);
    double h = (double)hf;
    #pragma unroll
    for (int o = 32; o; o >>= 1) h += __shfl_down(h, o, 64);
    if (lane == 0) hrow[r] = h;
}

// Cross partials: raw sum of s*log2(s) -> f64 atomics; y==JBLK rows do the
// exact-eps diagonal -> acc[1]. Last block (ticket) computes the final scalar.
__global__ __launch_bounds__(THREADS) void k_cross(
    const float* __restrict__ p1, const float* __restrict__ p2,
    double* __restrict__ acc, unsigned int* __restrict__ ticket,
    const double* __restrict__ hrow, float* __restrict__ out) {
    __shared__ double sd[4];
    __shared__ int is_last;
    int t = threadIdx.x;
    int bx = blockIdx.x;
    int by = blockIdx.y;
    int lane = t & 63, wid = t >> 6;
    double accd = 0.0;

    if (by < JBLK) {
        const float* ap = p1 + (size_t)bx * TI * DD + 4 * t;
        F4 a0, a1, a2, a3, a4, a5, a6, a7;
        a0.f = *(const float4*)(ap + 0 * DD);
        a1.f = *(const float4*)(ap + 1 * DD);
        a2.f = *(const float4*)(ap + 2 * DD);
        a3.f = *(const float4*)(ap + 3 * DD);
        a4.f = *(const float4*)(ap + 4 * DD);
        a5.f = *(const float4*)(ap + 5 * DD);
        a6.f = *(const float4*)(ap + 6 * DD);
        a7.f = *(const float4*)(ap + 7 * DD);

        v2f acc0 = {0.0f, 0.0f}, acc1 = {0.0f, 0.0f};
        const float* bp = p2 + (size_t)by * JCHUNK * DD + 4 * t;
        F4 b; b.f = *(const float4*)bp;
        #pragma unroll
        for (int j = 0; j < JCHUNK; ++j) {
            F4 bn;
            if (j + 1 < JCHUNK) bn.f = *(const float4*)(bp + (size_t)(j + 1) * DD);
            else                bn.f = b.f;
            #define ELT(A) { \
                v2f s0 = A.h[0] + b.h[0]; \
                v2f s1 = A.h[1] + b.h[1]; \
                v2f l0, l1; \
                l0.x = RLOG2(s0.x); l0.y = RLOG2(s0.y); \
                l1.x = RLOG2(s1.x); l1.y = RLOG2(s1.y); \
                acc0 = s0 * l0 + acc0; \
                acc1 = s1 * l1 + acc1; }
            ELT(a0) ELT(a1) ELT(a2) ELT(a3) ELT(a4) ELT(a5) ELT(a6) ELT(a7)
            #undef ELT
            b = bn;
        }
        accd = ((double)acc0.x + (double)acc0.y) + ((double)acc1.x + (double)acc1.y);
    } else {
        #pragma unroll
        for (int k = 0; k < TI; ++k) {
            int i = bx * TI + k;
            float4 a = *(const float4*)(p1 + (size_t)i * DD + 4 * t);
            float4 b = *(const float4*)(p2 + (size_t)i * DD + 4 * t);
            float sx = a.x + b.x, sy = a.y + b.y, sz = a.z + b.z, sw = a.w + b.w;
            float part = 0.0f;
            part = fmaf(sx, RLOG2(fmaf(0.5f, sx, EPSF)), part);
            part = fmaf(sy, RLOG2(fmaf(0.5f, sy, EPSF)), part);
            part = fmaf(sz, RLOG2(fmaf(0.5f, sz, EPSF)), part);
            part = fmaf(sw, RLOG2(fmaf(0.5f, sw, EPSF)), part);
            accd += (double)part;
        }
    }

    #pragma unroll
    for (int o = 32; o; o >>= 1) accd += __shfl_down(accd, o, 64);
    if (lane == 0) sd[wid] = accd;
    __syncthreads();
    if (t == 0) {
        double v = sd[0] + sd[1] + sd[2];
        atomicAdd((by < JBLK) ? &acc[2] : &acc[1], v);
        __threadfence();
        unsigned int old = atomicAdd(ticket, 1u);
        is_last = (old == (unsigned int)(NBLOCKS - 1)) ? 1 : 0;
    }
    __syncthreads();

    if (is_last) {
        // Final reduction: SH from hrow (written by previous kernel), Cd/Ct from acc.
        double h = 0.0;
        for (int i = t; i < 2 * NN; i += THREADS) h += hrow[i];
        #pragma unroll
        for (int o = 32; o; o >>= 1) h += __shfl_down(h, o, 64);
        if (lane == 0) sd[wid] = h;
        __syncthreads();
        if (t == 0) {
            double SH = (sd[0] + sd[1] + sd[2]) * LN2;
            __threadfence();
            double Cd   = atomicAdd(&acc[1], 0.0) * LN2;
            double Craw = atomicAdd(&acc[2], 0.0);
            double corr = 2.0 * 1e-8 * (double)DD * (double)NN * (double)NN / LN2;
            double Ct = (Craw - 2.0 * (double)NN * (double)NN + corr) * LN2;
            double diag_sum  = 0.5 * (SH - Cd);
            double total_sum = 0.5 * ((double)NN * SH - Ct);
            double pos = diag_sum / (double)NN;
            double neg = -(total_sum - diag_sum) / ((double)NN * (double)NN - (double)NN);
            out[0] = (float)(pos + neg);
        }
    }
}

extern "C" void kernel_launch(void* const* d_in, const int* in_sizes, int n_in,
                              void* d_out, int out_size, void* d_ws, size_t ws_size,
                              hipStream_t stream) {
    const float* z1 = (const float*)d_in[0];
    const float* z2 = (const float*)d_in[1];
    char* ws = (char*)d_ws;
    double*       acc    = (double*)(ws);
    unsigned int* ticket = (unsigned int*)(ws + 64);
    double*       hrow   = (double*)(ws + 128);
    float*        p1     = (float*)(ws + 32768);
    float*        p2     = p1 + (size_t)NN * DD;
    float* out = (float*)d_out;

    k_softmax<<<(2 * NN) / 4, 256, 0, stream>>>(z1, z2, p1, p2, hrow, acc, ticket);
    k_cross<<<dim3(IBLK, JBLK + 1), THREADS, 0, stream>>>(p1, p2, acc, ticket, hrow, out);
}

// Round 11
// 86.028 us; speedup vs baseline: 1.3505x; 1.3505x over previous
//
#include <hip/hip_runtime.h>

#define NN 512
#define DD 768
#define EPSF 1e-8f
#define TI 8
#define JCHUNK 16
#define JBLK (NN / JCHUNK)   // 32
#define IBLK (NN / TI)       // 64
#define THREADS 192
#define LN2 0.6931471805599453
#define LOG2E 1.4426950408889634f

#define RLOG2(x) __builtin_amdgcn_logf(x)
#define REXP2(x) __builtin_amdgcn_exp2f(x)

typedef float v2f __attribute__((ext_vector_type(2)));
union F4 { float4 f; v2f h[2]; };

// ws layout (bytes):
//   hrow  @ 0      : 1024 doubles (per-row H, log2 units)
//   cpart @ 8192   : IBLK*JBLK = 2048 doubles (cross partials, raw sum s*log2(s))
//   dpart @ 24576  : IBLK = 64 doubles (diag partials, exact-eps, log2 units)
//   p1    @ 32768  : 512*768 floats;  p2 after p1
//
// Cross identity:  sum_d s*log2(s/2+eps) = sum_d s*log2(s) - sum_d s + eps-term;
// summed over (i,j): sum s = 2*N^2 exactly, eps term -> 2*EPS*D*N^2/ln2 (analytic).
//
// Journal (why this shape):
//  - R10: global f64 atomics from all cross blocks + ticket/fence = 3x regression. Use
//    partial-sum STORES + tiny k_final kernel.
//  - R6/R8/R10: deep/unrolled b-prefetch lets the scheduler collapse prefetch distance
//    or blow registers; rolled j-loop with single-step prefetch is the sweet spot.
//  - R9: VOP3P packed adds/fmas in the hot loop: -1 us. Keep.

// One WAVE per row. 12 elements/lane, shuffle-only reductions.
__global__ __launch_bounds__(256) void k_softmax(
    const float* __restrict__ z1, const float* __restrict__ z2,
    float* __restrict__ p1, float* __restrict__ p2, double* __restrict__ hrow) {
    int t = threadIdx.x;
    int lane = t & 63, w = t >> 6;
    int r = blockIdx.x * 4 + w;
    const float* z = (r < NN) ? (z1 + (size_t)r * DD) : (z2 + (size_t)(r - NN) * DD);
    float*       p = (r < NN) ? (p1 + (size_t)r * DD) : (p2 + (size_t)(r - NN) * DD);

    float4 v0 = *(const float4*)(z + 4 * lane);
    float4 v1 = *(const float4*)(z + 256 + 4 * lane);
    float4 v2 = *(const float4*)(z + 512 + 4 * lane);

    float m = fmaxf(fmaxf(fmaxf(v0.x, v0.y), fmaxf(v0.z, v0.w)),
             fmaxf(fmaxf(fmaxf(v1.x, v1.y), fmaxf(v1.z, v1.w)),
                   fmaxf(fmaxf(v2.x, v2.y), fmaxf(v2.z, v2.w))));
    #pragma unroll
    for (int o = 32; o; o >>= 1) m = fmaxf(m, __shfl_xor(m, o, 64));

    float mb = -m * LOG2E;
    float4 e0, e1, e2;
    e0.x = REXP2(fmaf(v0.x, LOG2E, mb)); e0.y = REXP2(fmaf(v0.y, LOG2E, mb));
    e0.z = REXP2(fmaf(v0.z, LOG2E, mb)); e0.w = REXP2(fmaf(v0.w, LOG2E, mb));
    e1.x = REXP2(fmaf(v1.x, LOG2E, mb)); e1.y = REXP2(fmaf(v1.y, LOG2E, mb));
    e1.z = REXP2(fmaf(v1.z, LOG2E, mb)); e1.w = REXP2(fmaf(v1.w, LOG2E, mb));
    e2.x = REXP2(fmaf(v2.x, LOG2E, mb)); e2.y = REXP2(fmaf(v2.y, LOG2E, mb));
    e2.z = REXP2(fmaf(v2.z, LOG2E, mb)); e2.w = REXP2(fmaf(v2.w, LOG2E, mb));

    double s = ((double)e0.x + (double)e0.y) + ((double)e0.z + (double)e0.w)
             + ((double)e1.x + (double)e1.y) + ((double)e1.z + (double)e1.w)
             + ((double)e2.x + (double)e2.y) + ((double)e2.z + (double)e2.w);
    #pragma unroll
    for (int o = 32; o; o >>= 1) s += __shfl_xor(s, o, 64);
    float invS = 1.0f / (float)s;

    float4 q0, q1, q2;
    q0.x = e0.x * invS; q0.y = e0.y * invS; q0.z = e0.z * invS; q0.w = e0.w * invS;
    q1.x = e1.x * invS; q1.y = e1.y * invS; q1.z = e1.z * invS; q1.w = e1.w * invS;
    q2.x = e2.x * invS; q2.y = e2.y * invS; q2.z = e2.z * invS; q2.w = e2.w * invS;
    *(float4*)(p + 4 * lane) = q0;
    *(float4*)(p + 256 + 4 * lane) = q1;
    *(float4*)(p + 512 + 4 * lane) = q2;

    float hf = 0.0f;
    hf = fmaf(q0.x, RLOG2(q0.x + EPSF), hf); hf = fmaf(q0.y, RLOG2(q0.y + EPSF), hf);
    hf = fmaf(q0.z, RLOG2(q0.z + EPSF), hf); hf = fmaf(q0.w, RLOG2(q0.w + EPSF), hf);
    hf = fmaf(q1.x, RLOG2(q1.x + EPSF), hf); hf = fmaf(q1.y, RLOG2(q1.y + EPSF), hf);
    hf = fmaf(q1.z, RLOG2(q1.z + EPSF), hf); hf = fmaf(q1.w, RLOG2(q1.w + EPSF), hf);
    hf = fmaf(q2.x, RLOG2(q2.x + EPSF), hf); hf = fmaf(q2.y, RLOG2(q2.y + EPSF), hf);
    hf = fmaf(q2.z, RLOG2(q2.z + EPSF), hf); hf = fmaf(q2.w, RLOG2(q2.w + EPSF), hf);
    double h = (double)hf;
    #pragma unroll
    for (int o = 32; o; o >>= 1) h += __shfl_down(h, o, 64);
    if (lane == 0) hrow[r] = h;
}

// Cross partials: raw sum of s*log2(s). grid = (IBLK, JBLK+1); y==JBLK does the
// exact-eps diagonal. Rolled j-loop, single-step b prefetch, VOP3P packed fp32.
__global__ __launch_bounds__(THREADS) void k_cross(
    const float* __restrict__ p1, const float* __restrict__ p2,
    double* __restrict__ cpart, double* __restrict__ dpart) {
    __shared__ double sd[4];
    int t = threadIdx.x;
    int bx = blockIdx.x;
    int by = blockIdx.y;
    int lane = t & 63, wid = t >> 6;
    double accd = 0.0;

    if (by < JBLK) {
        const float* ap = p1 + (size_t)bx * TI * DD + 4 * t;
        F4 a0, a1, a2, a3, a4, a5, a6, a7;
        a0.f = *(const float4*)(ap + 0 * DD);
        a1.f = *(const float4*)(ap + 1 * DD);
        a2.f = *(const float4*)(ap + 2 * DD);
        a3.f = *(const float4*)(ap + 3 * DD);
        a4.f = *(const float4*)(ap + 4 * DD);
        a5.f = *(const float4*)(ap + 5 * DD);
        a6.f = *(const float4*)(ap + 6 * DD);
        a7.f = *(const float4*)(ap + 7 * DD);

        v2f acc0 = {0.0f, 0.0f}, acc1 = {0.0f, 0.0f};
        const float* bp = p2 + (size_t)by * JCHUNK * DD + 4 * t;
        F4 b; b.f = *(const float4*)bp;
        for (int j = 0; j < JCHUNK; ++j) {
            F4 bn;
            bn.f = (j + 1 < JCHUNK) ? *(const float4*)(bp + (size_t)(j + 1) * DD) : b.f;
            #define ELT(A) { \
                v2f s0 = A.h[0] + b.h[0]; \
                v2f s1 = A.h[1] + b.h[1]; \
                v2f l0, l1; \
                l0.x = RLOG2(s0.x); l0.y = RLOG2(s0.y); \
                l1.x = RLOG2(s1.x); l1.y = RLOG2(s1.y); \
                acc0 = s0 * l0 + acc0; \
                acc1 = s1 * l1 + acc1; }
            ELT(a0) ELT(a1) ELT(a2) ELT(a3) ELT(a4) ELT(a5) ELT(a6) ELT(a7)
            #undef ELT
            b = bn;
        }
        accd = ((double)acc0.x + (double)acc0.y) + ((double)acc1.x + (double)acc1.y);
    } else {
        #pragma unroll
        for (int k = 0; k < TI; ++k) {
            int i = bx * TI + k;
            float4 a = *(const float4*)(p1 + (size_t)i * DD + 4 * t);
            float4 b = *(const float4*)(p2 + (size_t)i * DD + 4 * t);
            float sx = a.x + b.x, sy = a.y + b.y, sz = a.z + b.z, sw = a.w + b.w;
            float part = 0.0f;
            part = fmaf(sx, RLOG2(fmaf(0.5f, sx, EPSF)), part);
            part = fmaf(sy, RLOG2(fmaf(0.5f, sy, EPSF)), part);
            part = fmaf(sz, RLOG2(fmaf(0.5f, sz, EPSF)), part);
            part = fmaf(sw, RLOG2(fmaf(0.5f, sw, EPSF)), part);
            accd += (double)part;
        }
    }

    #pragma unroll
    for (int o = 32; o; o >>= 1) accd += __shfl_down(accd, o, 64);
    if (lane == 0) sd[wid] = accd;
    __syncthreads();
    if (t == 0) {
        double v = sd[0] + sd[1] + sd[2];
        if (by < JBLK) cpart[by * IBLK + bx] = v;
        else           dpart[bx] = v;
    }
}

__global__ __launch_bounds__(256) void k_final(
    const double* __restrict__ hrow, const double* __restrict__ cpart,
    const double* __restrict__ dpart, float* __restrict__ out) {
    __shared__ double sh[4], sc[4], sg[4];
    int t = threadIdx.x, lane = t & 63, wid = t >> 6;
    double h = 0.0, c = 0.0, d = 0.0;
    for (int i = t; i < 2 * NN; i += 256) h += hrow[i];
    for (int i = t; i < IBLK * JBLK; i += 256) c += cpart[i];
    if (t < IBLK) d = dpart[t];
    #pragma unroll
    for (int o = 32; o; o >>= 1) {
        h += __shfl_down(h, o, 64);
        c += __shfl_down(c, o, 64);
        d += __shfl_down(d, o, 64);
    }
    if (lane == 0) { sh[wid] = h; sc[wid] = c; sg[wid] = d; }
    __syncthreads();
    if (t == 0) {
        double Craw = sc[0] + sc[1] + sc[2] + sc[3];  // sum s*log2(s)
        double corr = 2.0 * 1e-8 * (double)DD * (double)NN * (double)NN / LN2;
        double Ct = (Craw - 2.0 * (double)NN * (double)NN + corr) * LN2;
        double SH = (sh[0] + sh[1] + sh[2] + sh[3]) * LN2;
        double Cd = (sg[0] + sg[1] + sg[2] + sg[3]) * LN2;
        double diag_sum  = 0.5 * (SH - Cd);
        double total_sum = 0.5 * ((double)NN * SH - Ct);
        double pos = diag_sum / (double)NN;
        double neg = -(total_sum - diag_sum) / ((double)NN * (double)NN - (double)NN);
        out[0] = (float)(pos + neg);
    }
}

extern "C" void kernel_launch(void* const* d_in, const int* in_sizes, int n_in,
                              void* d_out, int out_size, void* d_ws, size_t ws_size,
                              hipStream_t stream) {
    const float* z1 = (const float*)d_in[0];
    const float* z2 = (const float*)d_in[1];
    char* ws = (char*)d_ws;
    double* hrow  = (double*)(ws);
    double* cpart = (double*)(ws + 8192);
    double* dpart = (double*)(ws + 24576);
    float*  p1    = (float*)(ws + 32768);
    float*  p2    = p1 + (size_t)NN * DD;
    float* out = (float*)d_out;

    k_softmax<<<(2 * NN) / 4, 256, 0, stream>>>(z1, z2, p1, p2, hrow);
    k_cross<<<dim3(IBLK, JBLK + 1), THREADS, 0, stream>>>(p1, p2, cpart, dpart);
    k_final<<<1, 256, 0, stream>>>(hrow, cpart, dpart, out);
}

// Round 12
// 85.196 us; speedup vs baseline: 1.3637x; 1.0098x over previous
//
#include <hip/hip_runtime.h>

#define NN 512
#define DD 768
#define EPSF 1e-8f
#define TI 8
#define JCHUNK 16
#define JBLK (NN / JCHUNK)   // 32
#define IBLK (NN / TI)       // 64
#define THREADS 192
#define LN2 0.6931471805599453
#define LOG2E 1.4426950408889634f

#define RLOG2(x) __builtin_amdgcn_logf(x)
#define REXP2(x) __builtin_amdgcn_exp2f(x)

typedef float v2f __attribute__((ext_vector_type(2)));
union F4 { float4 f; v2f h[2]; };

// ws layout (bytes):
//   hrow  @ 0      : 1024 doubles (per-row H, log2 units)
//   cpart @ 8192   : IBLK*JBLK = 2048 doubles (cross partials, raw sum s*log2(s))
//   dpart @ 24576  : IBLK = 64 doubles (diag partials, exact-eps, log2 units)
//   p1    @ 32768  : 512*768 floats;  p2 after p1
//
// Cross identity:  sum_d s*log2(s/2+eps) = sum_d s*log2(s) - sum_d s + eps-term;
// summed over (i,j): sum s = 2*N^2 exactly, eps term -> 2*EPS*D*N^2/ln2 (analytic).
//
// Journal (why this shape):
//  - R10: global f64 atomics from all cross blocks + ticket/fence = 3x regression. Use
//    partial-sum STORES + tiny k_final kernel.
//  - R6/R8/R10: deep/unrolled b-prefetch lets the scheduler collapse prefetch distance
//    or blow registers; rolled j-loop with single-step prefetch is the sweet spot.
//  - R9: VOP3P packed adds/fmas in the hot loop: -1 us. Keep.
//  - R12: diag folded into by==0 blocks -> grid exactly 2048 = 8 blocks/CU (kills the
//    64-block 9th dispatch wave / tail).

// One WAVE per row. 12 elements/lane, shuffle-only reductions.
__global__ __launch_bounds__(256) void k_softmax(
    const float* __restrict__ z1, const float* __restrict__ z2,
    float* __restrict__ p1, float* __restrict__ p2, double* __restrict__ hrow) {
    int t = threadIdx.x;
    int lane = t & 63, w = t >> 6;
    int r = blockIdx.x * 4 + w;
    const float* z = (r < NN) ? (z1 + (size_t)r * DD) : (z2 + (size_t)(r - NN) * DD);
    float*       p = (r < NN) ? (p1 + (size_t)r * DD) : (p2 + (size_t)(r - NN) * DD);

    float4 v0 = *(const float4*)(z + 4 * lane);
    float4 v1 = *(const float4*)(z + 256 + 4 * lane);
    float4 v2 = *(const float4*)(z + 512 + 4 * lane);

    float m = fmaxf(fmaxf(fmaxf(v0.x, v0.y), fmaxf(v0.z, v0.w)),
             fmaxf(fmaxf(fmaxf(v1.x, v1.y), fmaxf(v1.z, v1.w)),
                   fmaxf(fmaxf(v2.x, v2.y), fmaxf(v2.z, v2.w))));
    #pragma unroll
    for (int o = 32; o; o >>= 1) m = fmaxf(m, __shfl_xor(m, o, 64));

    float mb = -m * LOG2E;
    float4 e0, e1, e2;
    e0.x = REXP2(fmaf(v0.x, LOG2E, mb)); e0.y = REXP2(fmaf(v0.y, LOG2E, mb));
    e0.z = REXP2(fmaf(v0.z, LOG2E, mb)); e0.w = REXP2(fmaf(v0.w, LOG2E, mb));
    e1.x = REXP2(fmaf(v1.x, LOG2E, mb)); e1.y = REXP2(fmaf(v1.y, LOG2E, mb));
    e1.z = REXP2(fmaf(v1.z, LOG2E, mb)); e1.w = REXP2(fmaf(v1.w, LOG2E, mb));
    e2.x = REXP2(fmaf(v2.x, LOG2E, mb)); e2.y = REXP2(fmaf(v2.y, LOG2E, mb));
    e2.z = REXP2(fmaf(v2.z, LOG2E, mb)); e2.w = REXP2(fmaf(v2.w, LOG2E, mb));

    double s = ((double)e0.x + (double)e0.y) + ((double)e0.z + (double)e0.w)
             + ((double)e1.x + (double)e1.y) + ((double)e1.z + (double)e1.w)
             + ((double)e2.x + (double)e2.y) + ((double)e2.z + (double)e2.w);
    #pragma unroll
    for (int o = 32; o; o >>= 1) s += __shfl_xor(s, o, 64);
    float invS = 1.0f / (float)s;

    float4 q0, q1, q2;
    q0.x = e0.x * invS; q0.y = e0.y * invS; q0.z = e0.z * invS; q0.w = e0.w * invS;
    q1.x = e1.x * invS; q1.y = e1.y * invS; q1.z = e1.z * invS; q1.w = e1.w * invS;
    q2.x = e2.x * invS; q2.y = e2.y * invS; q2.z = e2.z * invS; q2.w = e2.w * invS;
    *(float4*)(p + 4 * lane) = q0;
    *(float4*)(p + 256 + 4 * lane) = q1;
    *(float4*)(p + 512 + 4 * lane) = q2;

    float hf = 0.0f;
    hf = fmaf(q0.x, RLOG2(q0.x + EPSF), hf); hf = fmaf(q0.y, RLOG2(q0.y + EPSF), hf);
    hf = fmaf(q0.z, RLOG2(q0.z + EPSF), hf); hf = fmaf(q0.w, RLOG2(q0.w + EPSF), hf);
    hf = fmaf(q1.x, RLOG2(q1.x + EPSF), hf); hf = fmaf(q1.y, RLOG2(q1.y + EPSF), hf);
    hf = fmaf(q1.z, RLOG2(q1.z + EPSF), hf); hf = fmaf(q1.w, RLOG2(q1.w + EPSF), hf);
    hf = fmaf(q2.x, RLOG2(q2.x + EPSF), hf); hf = fmaf(q2.y, RLOG2(q2.y + EPSF), hf);
    hf = fmaf(q2.z, RLOG2(q2.z + EPSF), hf); hf = fmaf(q2.w, RLOG2(q2.w + EPSF), hf);
    double h = (double)hf;
    #pragma unroll
    for (int o = 32; o; o >>= 1) h += __shfl_down(h, o, 64);
    if (lane == 0) hrow[r] = h;
}

// Cross partials: raw sum of s*log2(s). grid = (IBLK, JBLK) = 2048 blocks exactly.
// by==0 blocks additionally compute the exact-eps diagonal for their 8 rows.
// Rolled j-loop, single-step b prefetch, VOP3P packed fp32.
__global__ __launch_bounds__(THREADS) void k_cross(
    const float* __restrict__ p1, const float* __restrict__ p2,
    double* __restrict__ cpart, double* __restrict__ dpart) {
    __shared__ double sd[4];
    __shared__ double sdd[4];
    int t = threadIdx.x;
    int bx = blockIdx.x;
    int by = blockIdx.y;
    int lane = t & 63, wid = t >> 6;

    const float* ap = p1 + (size_t)bx * TI * DD + 4 * t;
    F4 a0, a1, a2, a3, a4, a5, a6, a7;
    a0.f = *(const float4*)(ap + 0 * DD);
    a1.f = *(const float4*)(ap + 1 * DD);
    a2.f = *(const float4*)(ap + 2 * DD);
    a3.f = *(const float4*)(ap + 3 * DD);
    a4.f = *(const float4*)(ap + 4 * DD);
    a5.f = *(const float4*)(ap + 5 * DD);
    a6.f = *(const float4*)(ap + 6 * DD);
    a7.f = *(const float4*)(ap + 7 * DD);

    v2f acc0 = {0.0f, 0.0f}, acc1 = {0.0f, 0.0f};
    const float* bp = p2 + (size_t)by * JCHUNK * DD + 4 * t;
    F4 b; b.f = *(const float4*)bp;
    for (int j = 0; j < JCHUNK; ++j) {
        F4 bn;
        bn.f = (j + 1 < JCHUNK) ? *(const float4*)(bp + (size_t)(j + 1) * DD) : b.f;
        #define ELT(A) { \
            v2f s0 = A.h[0] + b.h[0]; \
            v2f s1 = A.h[1] + b.h[1]; \
            v2f l0, l1; \
            l0.x = RLOG2(s0.x); l0.y = RLOG2(s0.y); \
            l1.x = RLOG2(s1.x); l1.y = RLOG2(s1.y); \
            acc0 = s0 * l0 + acc0; \
            acc1 = s1 * l1 + acc1; }
        ELT(a0) ELT(a1) ELT(a2) ELT(a3) ELT(a4) ELT(a5) ELT(a6) ELT(a7)
        #undef ELT
        b = bn;
    }
    double accd = ((double)acc0.x + (double)acc0.y) + ((double)acc1.x + (double)acc1.y);

    #pragma unroll
    for (int o = 32; o; o >>= 1) accd += __shfl_down(accd, o, 64);
    if (lane == 0) sd[wid] = accd;

    // by==0 blocks also do the exact-eps diagonal for rows bx*TI..bx*TI+7.
    if (by == 0) {
        double dd = 0.0;
        #pragma unroll
        for (int k = 0; k < TI; ++k) {
            int i = bx * TI + k;
            float4 a = *(const float4*)(p1 + (size_t)i * DD + 4 * t);
            float4 bb = *(const float4*)(p2 + (size_t)i * DD + 4 * t);
            float sx = a.x + bb.x, sy = a.y + bb.y, sz = a.z + bb.z, sw = a.w + bb.w;
            float part = 0.0f;
            part = fmaf(sx, RLOG2(fmaf(0.5f, sx, EPSF)), part);
            part = fmaf(sy, RLOG2(fmaf(0.5f, sy, EPSF)), part);
            part = fmaf(sz, RLOG2(fmaf(0.5f, sz, EPSF)), part);
            part = fmaf(sw, RLOG2(fmaf(0.5f, sw, EPSF)), part);
            dd += (double)part;
        }
        #pragma unroll
        for (int o = 32; o; o >>= 1) dd += __shfl_down(dd, o, 64);
        if (lane == 0) sdd[wid] = dd;
    }

    __syncthreads();
    if (t == 0) {
        cpart[by * IBLK + bx] = sd[0] + sd[1] + sd[2];
        if (by == 0) dpart[bx] = sdd[0] + sdd[1] + sdd[2];
    }
}

__global__ __launch_bounds__(256) void k_final(
    const double* __restrict__ hrow, const double* __restrict__ cpart,
    const double* __restrict__ dpart, float* __restrict__ out) {
    __shared__ double sh[4], sc[4], sg[4];
    int t = threadIdx.x, lane = t & 63, wid = t >> 6;
    double h = 0.0, c = 0.0, d = 0.0;
    for (int i = t; i < 2 * NN; i += 256) h += hrow[i];
    for (int i = t; i < IBLK * JBLK; i += 256) c += cpart[i];
    if (t < IBLK) d = dpart[t];
    #pragma unroll
    for (int o = 32; o; o >>= 1) {
        h += __shfl_down(h, o, 64);
        c += __shfl_down(c, o, 64);
        d += __shfl_down(d, o, 64);
    }
    if (lane == 0) { sh[wid] = h; sc[wid] = c; sg[wid] = d; }
    __syncthreads();
    if (t == 0) {
        double Craw = sc[0] + sc[1] + sc[2] + sc[3];  // sum s*log2(s)
        double corr = 2.0 * 1e-8 * (double)DD * (double)NN * (double)NN / LN2;
        double Ct = (Craw - 2.0 * (double)NN * (double)NN + corr) * LN2;
        double SH = (sh[0] + sh[1] + sh[2] + sh[3]) * LN2;
        double Cd = (sg[0] + sg[1] + sg[2] + sg[3]) * LN2;
        double diag_sum  = 0.5 * (SH - Cd);
        double total_sum = 0.5 * ((double)NN * SH - Ct);
        double pos = diag_sum / (double)NN;
        double neg = -(total_sum - diag_sum) / ((double)NN * (double)NN - (double)NN);
        out[0] = (float)(pos + neg);
    }
}

extern "C" void kernel_launch(void* const* d_in, const int* in_sizes, int n_in,
                              void* d_out, int out_size, void* d_ws, size_t ws_size,
                              hipStream_t stream) {
    const float* z1 = (const float*)d_in[0];
    const float* z2 = (const float*)d_in[1];
    char* ws = (char*)d_ws;
    double* hrow  = (double*)(ws);
    double* cpart = (double*)(ws + 8192);
    double* dpart = (double*)(ws + 24576);
    float*  p1    = (float*)(ws + 32768);
    float*  p2    = p1 + (size_t)NN * DD;
    float* out = (float*)d_out;

    k_softmax<<<(2 * NN) / 4, 256, 0, stream>>>(z1, z2, p1, p2, hrow);
    k_cross<<<dim3(IBLK, JBLK), THREADS, 0, stream>>>(p1, p2, cpart, dpart);
    k_final<<<1, 256, 0, stream>>>(hrow, cpart, dpart, out);
}